// Round 1
// baseline (204.662 us; speedup 1.0000x reference)
//
#include <hip/hip_runtime.h>
#include <math.h>

// iFreqProj: u[b,n] = Re[ (1/F^2) * sum_ij fm[n,i,j] * exp(i*2pi*(x0*i + x1*j)) ]
// where fm = mean_b f[b]. Phase is separable: exp(i2pi x0 i) * exp(i2pi x1 j).
// Pass 1: batch-mean (memory-bound, 128 MiB read). Pass 2: tiny contraction.

#define NF 512
#define NB 32
#define SLICE  (2 * NF * NF * 2)   // floats per batch item = 1,048,576 (4 MiB)
#define SLICE4 (SLICE / 4)         // float4 per batch item = 262,144
#define CH 8                       // row chunks per (b,n)
#define ROWS (NF / CH)             // 64 rows per chunk

__global__ __launch_bounds__(256) void batch_mean_kernel(
    const float4* __restrict__ f4, float4* __restrict__ fm4) {
  const int idx = blockIdx.x * 256 + threadIdx.x;   // grid exactly covers SLICE4
  float4 acc = f4[idx];
  #pragma unroll
  for (int b = 1; b < NB; ++b) {
    float4 v = f4[(size_t)b * SLICE4 + idx];
    acc.x += v.x; acc.y += v.y; acc.z += v.z; acc.w += v.w;
  }
  const float s = 1.0f / NB;   // exact power of two
  acc.x *= s; acc.y *= s; acc.z *= s; acc.w *= s;
  fm4[idx] = acc;
}

// One block per (b, n, chunk). 256 threads; thread t owns columns 2t, 2t+1.
__global__ __launch_bounds__(256) void contract_kernel(
    const float* __restrict__ fm, const float* __restrict__ x,
    float* __restrict__ out) {
  __shared__ float2 p1s[NF];
  __shared__ float2 p0s[ROWS];
  __shared__ float wsum[4];

  const int tid   = threadIdx.x;
  const int bx    = blockIdx.x;
  const int chunk = bx & (CH - 1);
  const int n     = (bx >> 3) & 1;
  const int b     = bx >> 4;

  const float x0 = x[2 * b + 0];
  const float x1 = x[2 * b + 1];
  const float TWO_PI = 6.28318530717958647692f;

  // p1[j] = exp(i*2pi*x1*j), range-reduced via fract (revolutions)
  for (int j = tid; j < NF; j += 256) {
    float rev = x1 * (float)j;
    float r = rev - floorf(rev);
    float s, c; sincosf(TWO_PI * r, &s, &c);
    p1s[j] = make_float2(c, s);
  }
  const int i0 = chunk * ROWS;
  if (tid < ROWS) {
    float rev = x0 * (float)(i0 + tid);
    float r = rev - floorf(rev);
    float s, c; sincosf(TWO_PI * r, &s, &c);
    p0s[tid] = make_float2(c, s);
  }
  __syncthreads();

  const float2 P1a = p1s[2 * tid];
  const float2 P1b = p1s[2 * tid + 1];
  const float4* frow = (const float4*)(fm + (size_t)n * NF * NF * 2);

  float acc = 0.0f;
  #pragma unroll 4
  for (int ir = 0; ir < ROWS; ++ir) {
    const int i = i0 + ir;
    // float4 = (re,im) of columns 2t and 2t+1 of row i: 1 KiB/wave coalesced
    float4 v = frow[(size_t)i * (NF / 2) + tid];
    float2 p0 = p0s[ir];                 // uniform addr -> LDS broadcast
    float wr = v.x * P1a.x - v.y * P1a.y + v.z * P1b.x - v.w * P1b.y;
    float wi = v.x * P1a.y + v.y * P1a.x + v.z * P1b.y + v.w * P1b.x;
    acc += wr * p0.x - wi * p0.y;        // Re[(fc.p1) * p0]
  }

  // 64-lane wave reduce, then 4 waves via LDS
  #pragma unroll
  for (int o = 32; o > 0; o >>= 1) acc += __shfl_xor(acc, o, 64);
  const int wave = tid >> 6;
  if ((tid & 63) == 0) wsum[wave] = acc;
  __syncthreads();
  if (tid == 0) {
    float t = wsum[0] + wsum[1] + wsum[2] + wsum[3];
    atomicAdd(&out[b * 2 + n], t * (1.0f / (float)(NF * NF)));
  }
}

// Fallback if d_ws can't hold fm (4 MiB): contract directly against f,
// folding the batch mean into the inner loop (reads f 32x, L3-cached).
__global__ __launch_bounds__(256) void contract_direct_kernel(
    const float4* __restrict__ f4, const float* __restrict__ x,
    float* __restrict__ out) {
  __shared__ float2 p1s[NF];
  __shared__ float2 p0s[ROWS];
  __shared__ float wsum[4];

  const int tid   = threadIdx.x;
  const int bx    = blockIdx.x;
  const int chunk = bx & (CH - 1);
  const int n     = (bx >> 3) & 1;
  const int b     = bx >> 4;

  const float x0 = x[2 * b + 0];
  const float x1 = x[2 * b + 1];
  const float TWO_PI = 6.28318530717958647692f;

  for (int j = tid; j < NF; j += 256) {
    float rev = x1 * (float)j;
    float r = rev - floorf(rev);
    float s, c; sincosf(TWO_PI * r, &s, &c);
    p1s[j] = make_float2(c, s);
  }
  const int i0 = chunk * ROWS;
  if (tid < ROWS) {
    float rev = x0 * (float)(i0 + tid);
    float r = rev - floorf(rev);
    float s, c; sincosf(TWO_PI * r, &s, &c);
    p0s[tid] = make_float2(c, s);
  }
  __syncthreads();

  const float2 P1a = p1s[2 * tid];
  const float2 P1b = p1s[2 * tid + 1];

  float acc = 0.0f;
  for (int ir = 0; ir < ROWS; ++ir) {
    const int i = i0 + ir;
    const size_t base = (size_t)n * (NF * NF / 2) + (size_t)i * (NF / 2) + tid;
    float4 v = make_float4(0.f, 0.f, 0.f, 0.f);
    for (int bb = 0; bb < NB; ++bb) {
      float4 t = f4[(size_t)bb * SLICE4 + base];
      v.x += t.x; v.y += t.y; v.z += t.z; v.w += t.w;
    }
    float2 p0 = p0s[ir];
    float wr = v.x * P1a.x - v.y * P1a.y + v.z * P1b.x - v.w * P1b.y;
    float wi = v.x * P1a.y + v.y * P1a.x + v.z * P1b.y + v.w * P1b.x;
    acc += wr * p0.x - wi * p0.y;
  }

  #pragma unroll
  for (int o = 32; o > 0; o >>= 1) acc += __shfl_xor(acc, o, 64);
  const int wave = tid >> 6;
  if ((tid & 63) == 0) wsum[wave] = acc;
  __syncthreads();
  if (tid == 0) {
    float t = wsum[0] + wsum[1] + wsum[2] + wsum[3];
    atomicAdd(&out[b * 2 + n], t * (1.0f / ((float)NB * (float)(NF * NF))));
  }
}

extern "C" void kernel_launch(void* const* d_in, const int* in_sizes, int n_in,
                              void* d_out, int out_size, void* d_ws, size_t ws_size,
                              hipStream_t stream) {
  const float* f = (const float*)d_in[0];
  const float* x = (const float*)d_in[1];
  float* out = (float*)d_out;

  // d_out is poisoned before every launch; we accumulate with atomics.
  hipMemsetAsync(out, 0, (size_t)out_size * sizeof(float), stream);

  const size_t fm_bytes = (size_t)SLICE * sizeof(float);   // 4 MiB
  if (ws_size >= fm_bytes) {
    float* fm = (float*)d_ws;
    batch_mean_kernel<<<SLICE4 / 256, 256, 0, stream>>>(
        (const float4*)f, (float4*)fm);
    contract_kernel<<<NB * 2 * CH, 256, 0, stream>>>(fm, x, out);
  } else {
    contract_direct_kernel<<<NB * 2 * CH, 256, 0, stream>>>(
        (const float4*)f, x, out);
  }
}

// Round 2
// 193.061 us; speedup vs baseline: 1.0601x; 1.0601x over previous
//
#include <hip/hip_runtime.h>
#include <math.h>

// u[b,n] = Re[ (1/(NB*F^2)) * sum_bb sum_ij f[bb,n,i,j] * exp(i*2pi*(x0[b]*i + x1[b]*j)) ]
// Separable phase: exp(i2pi x0 i) * exp(i2pi x1 j).
// Kernel 1 (HBM-bound, one pass over f = 134 MiB):
//   per row (n,i): batch-sum row into LDS, then S[b,n,i] = sum_j row[j]*p1[b,j]
//   computed with thread = (j-chunk q, b) mapping and a complex recurrence
//   p1[b,j+1] = p1[b,j]*e^{i2pi x1} (2 sincos/thread instead of 64).
// Kernel 2 (tiny): u[b,n] = (1/(NB*F^2)) * sum_i Re(p0[b,i] * S[b,n,i]).
// Kernel 2 writes every output -> no memset, no atomics.

#define NF 512
#define NB 32
#define SLICE4 262144          // float4 per batch item (2*512*512*2/4)
#define TWO_PI 6.28318530717958647692f

// grid 1024 blocks = (n,i); 256 threads.
__global__ __launch_bounds__(256) void rowsum_kernel(
    const float4* __restrict__ f4, const float* __restrict__ x,
    float2* __restrict__ g) {
  __shared__ float4 row4[256];        // one (n,i) row: 512 complex = 4 KiB
  __shared__ float  part[4][NB][2];   // per-wave partials
  __shared__ float  xs[2 * NB];

  const int tid = threadIdx.x;
  const int bx  = blockIdx.x;
  const int n   = bx >> 9;
  const int i   = bx & 511;

  if (tid < 2 * NB) xs[tid] = x[tid];

  // ---- phase 1: batch-sum of this row (the single HBM pass) ----
  const size_t rowbase = (size_t)(n * NF + i) * 256 + tid;  // float4 units
  float4 a = f4[rowbase];
  #pragma unroll
  for (int bb = 1; bb < NB; ++bb) {
    float4 v = f4[(size_t)bb * SLICE4 + rowbase];
    a.x += v.x; a.y += v.y; a.z += v.z; a.w += v.w;
  }
  row4[tid] = a;
  __syncthreads();

  // ---- phase 2: contract row against p1[b,:] for all 32 b ----
  const int b = tid & 31;       // batch index
  const int q = tid >> 5;       // j-chunk: j in [q*64, q*64+64)
  const float x1 = xs[2 * b + 1];

  float rev = x1 * (float)(q * 64);
  rev -= floorf(rev);
  float s, c;
  sincosf(TWO_PI * rev, &s, &c);
  float pr = c, pim = s;                       // p1[b, q*64]
  rev = x1 - floorf(x1);
  sincosf(TWO_PI * rev, &s, &c);
  const float wr = c, wi = s;                  // e^{i*2pi*x1}

  const float2* row2 = (const float2*)row4;
  float Sr = 0.f, Si = 0.f;
  #pragma unroll 8
  for (int jj = 0; jj < 64; ++jj) {
    float2 v = row2[q * 64 + jj];              // 32 lanes same addr: broadcast
    Sr += v.x * pr - v.y * pim;
    Si += v.x * pim + v.y * pr;
    float npr = pr * wr - pim * wi;            // p *= w
    float npi = pr * wi + pim * wr;
    pr = npr; pim = npi;
  }

  // q-pair within wave, then 4 waves via LDS
  Sr += __shfl_xor(Sr, 32, 64);
  Si += __shfl_xor(Si, 32, 64);
  const int w = tid >> 6;
  if ((tid & 63) < 32) { part[w][b][0] = Sr; part[w][b][1] = Si; }
  __syncthreads();

  if (tid < 32) {
    float sr = part[0][tid][0] + part[1][tid][0] + part[2][tid][0] + part[3][tid][0];
    float si = part[0][tid][1] + part[1][tid][1] + part[2][tid][1] + part[3][tid][1];
    g[(((tid << 1) | n) << 9) | i] = make_float2(sr, si);   // S[b][n][i]
  }
}

// grid 64 blocks = (b,n); 256 threads; writes every output element.
__global__ __launch_bounds__(256) void colsum_kernel(
    const float2* __restrict__ g, const float* __restrict__ x,
    float* __restrict__ out) {
  __shared__ float wsum[4];
  const int tid = threadIdx.x;
  const int bn  = blockIdx.x;       // b*2 + n
  const int b   = bn >> 1;
  const float x0 = x[2 * b];

  float acc = 0.f;
  #pragma unroll
  for (int k = 0; k < 2; ++k) {
    const int i = tid + k * 256;
    float2 Sv = g[(bn << 9) | i];
    float rev = x0 * (float)i;
    rev -= floorf(rev);
    float s, c;
    sincosf(TWO_PI * rev, &s, &c);
    acc += c * Sv.x - s * Sv.y;     // Re(p0 * S)
  }
  #pragma unroll
  for (int o = 32; o > 0; o >>= 1) acc += __shfl_xor(acc, o, 64);
  if ((tid & 63) == 0) wsum[tid >> 6] = acc;
  __syncthreads();
  if (tid == 0)
    out[bn] = (wsum[0] + wsum[1] + wsum[2] + wsum[3]) * (1.0f / 8388608.0f);
    // 1/(NB * F^2) = 1/2^23, exact
}

extern "C" void kernel_launch(void* const* d_in, const int* in_sizes, int n_in,
                              void* d_out, int out_size, void* d_ws, size_t ws_size,
                              hipStream_t stream) {
  const float* f = (const float*)d_in[0];
  const float* x = (const float*)d_in[1];
  float* out = (float*)d_out;
  float2* g = (float2*)d_ws;        // needs 64*512*8 = 256 KiB

  rowsum_kernel<<<2 * NF, 256, 0, stream>>>((const float4*)f, x, g);
  colsum_kernel<<<NB * 2, 256, 0, stream>>>(g, x, out);
}